// Round 5
// baseline (618.168 us; speedup 1.0000x reference)
//
#include <hip/hip_runtime.h>
#include <hip/hip_bf16.h>

typedef __attribute__((ext_vector_type(8))) short short8;
typedef __attribute__((ext_vector_type(4))) float floatx4;
typedef __attribute__((ext_vector_type(8))) unsigned short ushortx8;
typedef __attribute__((ext_vector_type(4))) unsigned short ushortx4;
typedef unsigned short u16;

#define NH 16
#define SEQ 2048
#define CHUNK 128
#define NCHUNK 16
#define NBLK 384   // 1.5 blocks/CU; <= 2/CU capacity (LDS 59.6KB) so all co-resident

__device__ __forceinline__ u16 f2bf(float f) {
    union { float f; unsigned u; } v; v.f = f;
    unsigned r = v.u + 0x7fffu + ((v.u >> 16) & 1u);
    return (u16)(r >> 16);
}
__device__ __forceinline__ float bf2f(u16 u) {
    union { unsigned u; float f; } v; v.u = ((unsigned)u) << 16;
    return v.f;
}
__device__ __forceinline__ void gl_lds16(const u16* g, u16* l) {
    __builtin_amdgcn_global_load_lds(
        (const __attribute__((address_space(1))) void*)g,
        (__attribute__((address_space(3))) void*)l,
        16, 0, 0);
}

// Software grid barrier. Counters zeroed by hipMemsetAsync before launch.
// Device-scope release fence -> arrive -> acquire spin -> acquire fence.
// Sound because all NBLK blocks are co-resident (2 blocks/CU resources).
__device__ __forceinline__ void gridbar(int* __restrict__ bar, int phase) {
    __syncthreads();
    __threadfence();  // release: my global writes visible device-wide
    if (threadIdx.x == 0) {
        atomicAdd(&bar[phase], 1);  // device scope [m20]
        int guard = 0;
        while (__hip_atomic_load(&bar[phase], __ATOMIC_ACQUIRE,
                                 __HIP_MEMORY_SCOPE_AGENT) < NBLK) {
            __builtin_amdgcn_s_sleep(8);
            if (++guard > 100000000) break;  // fail-safe: wrong answer, not hang
        }
    }
    __syncthreads();
    __threadfence();  // acquire: invalidate caches before cross-block reads
}

// ---------------- phase 1: one 128x128 qkv tile -----------------------------
__device__ __forceinline__ void qkv_tile(int tile, u16* smem,
    const u16* __restrict__ A, const u16* __restrict__ Bm,
    u16* __restrict__ qkb, u16* __restrict__ kT_b, u16* __restrict__ vT_b)
{
    u16* As = smem;            // [128][64]
    u16* Bs = smem + 8192;     // [128][64]
    const int n0 = (tile % 24) * 128, m0 = (tile / 24) * 128;
    const int t = threadIdx.x;
    const int lane = t & 63, wave = t >> 6;
    const int ln = lane & 15, q4 = lane >> 4;
    const int wm = (wave >> 1) * 64, wn = (wave & 1) * 64;
    const int r_in = t >> 3;
    const int csw = (((t & 7) ^ (r_in & 7)) << 3);

    const u16* Ag = A + (size_t)(m0 + r_in) * 1024 + csw;
    const u16* Bg = Bm + (size_t)(n0 + r_in) * 1024 + csw;

    floatx4 acc[4][4];
#pragma unroll
    for (int i = 0; i < 4; i++)
#pragma unroll
        for (int j = 0; j < 4; j++) acc[i][j] = (floatx4)0.0f;

    for (int k0 = 0; k0 < 1024; k0 += 64) {
        __syncthreads();
#pragma unroll
        for (int i = 0; i < 4; i++)
            gl_lds16(Ag + (size_t)i * 32 * 1024, &As[i * 2048 + t * 8]);
#pragma unroll
        for (int i = 0; i < 4; i++)
            gl_lds16(Bg + (size_t)i * 32 * 1024, &Bs[i * 2048 + t * 8]);
        Ag += 64; Bg += 64;
        __syncthreads();
#pragma unroll
        for (int s = 0; s < 2; s++) {
            const int rc = (((s * 4 + q4) ^ (ln & 7)) << 3);
            short8 af[4], bfr[4];
#pragma unroll
            for (int i = 0; i < 4; i++)
                af[i] = *(const short8*)&As[(wm + i * 16 + ln) * 64 + rc];
#pragma unroll
            for (int j = 0; j < 4; j++)
                bfr[j] = *(const short8*)&Bs[(wn + j * 16 + ln) * 64 + rc];
#pragma unroll
            for (int i = 0; i < 4; i++)
#pragma unroll
                for (int j = 0; j < 4; j++)
                    acc[i][j] = __builtin_amdgcn_mfma_f32_16x16x32_bf16(af[i], bfr[j], acc[i][j], 0, 0, 0);
        }
    }
    const int grp = n0 >> 10;  // 0=q 1=k 2=v (block-uniform)
#pragma unroll
    for (int i = 0; i < 4; i++)
#pragma unroll
        for (int j = 0; j < 4; j++) {
            const int mb = m0 + wm + i * 16 + q4 * 4;
            const int n = n0 + wn + j * 16 + ln;
            const int nh = n & 1023, h = nh >> 6, e = nh & 63;
            float vals[4];
#pragma unroll
            for (int r = 0; r < 4; r++) {
                float v = acc[i][j][r];
                if (grp < 2) v = (v > 0.f) ? (v + 1.f) : __expf(v);
                vals[r] = v;
            }
            if (grp == 0) {
#pragma unroll
                for (int r = 0; r < 4; r++) qkb[(size_t)(mb + r) * 2048 + nh] = f2bf(vals[r]);
            } else if (grp == 1) {
#pragma unroll
                for (int r = 0; r < 4; r++) qkb[(size_t)(mb + r) * 2048 + 1024 + nh] = f2bf(vals[r]);
                ushortx4 u = { f2bf(vals[0]), f2bf(vals[1]), f2bf(vals[2]), f2bf(vals[3]) };
                *(ushortx4*)&kT_b[(size_t)(h * 64 + e) * 2048 + mb] = u;
            } else {
                ushortx4 u = { f2bf(vals[0]), f2bf(vals[1]), f2bf(vals[2]), f2bf(vals[3]) };
                *(ushortx4*)&vT_b[(size_t)(h * 64 + e) * 2048 + mb] = u;
            }
        }
    __syncthreads();  // LDS reads done before any reuse
}

// ---------------- phase 2: chunk_stats (R3-verified body) -------------------
__device__ __forceinline__ void chunk_stats_body(int c, int h, u16* smem,
    const u16* __restrict__ kT_b, const u16* __restrict__ vT_b,
    float* __restrict__ S_ws, float* __restrict__ ksum_ws)
{
    u16* kT_l = smem;          // [64][128]
    u16* vT_l = smem + 8192;   // [64][128]
    const int t = threadIdx.x;
    const int lane = t & 63, w = t >> 6;
    const int ln = lane & 15, q4 = lane >> 4;
#pragma unroll
    for (int i = 0; i < 4; i++) {
        const int d0 = w * 16 + i * 4 + (lane >> 4);
        const int cc = lane & 15;
        const size_t gsrc = (size_t)(h * 64 + d0) * 2048 + c * 128 + ((cc ^ (d0 & 7)) << 3);
        gl_lds16(kT_b + gsrc, &kT_l[(w * 16 + i * 4) * 128 + lane * 8]);
        gl_lds16(vT_b + gsrc, &vT_l[(w * 16 + i * 4) * 128 + lane * 8]);
    }
    __syncthreads();
    floatx4 sacc[4];
#pragma unroll
    for (int j = 0; j < 4; j++) sacc[j] = (floatx4)0.0f;
#pragma unroll
    for (int ks = 0; ks < 4; ks++) {
        const int rc = (((ks * 4 + q4) ^ (ln & 7)) << 3);
        short8 af = *(const short8*)&kT_l[(w * 16 + ln) * 128 + rc];
#pragma unroll
        for (int j = 0; j < 4; j++) {
            short8 bfr = *(const short8*)&vT_l[(j * 16 + ln) * 128 + rc];
            sacc[j] = __builtin_amdgcn_mfma_f32_16x16x32_bf16(af, bfr, sacc[j], 0, 0, 0);
        }
    }
    float* Sp = S_ws + ((size_t)(h * NCHUNK + c) << 12);
#pragma unroll
    for (int j = 0; j < 4; j++)
#pragma unroll
        for (int r = 0; r < 4; r++) {
            int d = w * 16 + q4 * 4 + r;
            int e = j * 16 + ln;
            Sp[e * 64 + d] = sacc[j][r];  // S^T [e][d]
        }
    if (t < 64) {  // ksum[d] (swizzle permutes within row; sum invariant)
        float s = 0.f;
#pragma unroll
        for (int cc = 0; cc < 16; cc++) {
            ushortx8 v8 = *(const ushortx8*)&kT_l[t * 128 + cc * 8];
#pragma unroll
            for (int jj = 0; jj < 8; jj++) s += bf2f(v8[jj]);
        }
        ksum_ws[(h * NCHUNK + c) * 64 + t] = s;
    }
    __syncthreads();
}

// ---------------- phase 3: attention per (c,h) (R3-verified body) -----------
__device__ __forceinline__ void attn_body(int c, int h, u16* smem,
    const u16* __restrict__ qkb, const u16* __restrict__ vT_b,
    const float* __restrict__ S_ws, const float* __restrict__ ksum_ws,
    u16* __restrict__ attnb)
{
    u16* q_l   = smem;           // [128][64] swizzled
    u16* k_l   = smem + 8192;    // [128][64] swizzled
    u16* kvT_l = smem + 16384;   // [64][72]
    u16* P_l   = smem;           // [128][136] aliases q+k+kvT when dead
    u16* vT_l  = smem + 20992;   // [64][128] swizzled
    float* kpref  = (float*)(smem + 29184);  // [64]
    float* denom2 = kpref + 64;              // [2][128]

    const int t = threadIdx.x;
    const int lane = t & 63, w = t >> 6;
    const int ln = lane & 15, q4 = lane >> 4;

#pragma unroll
    for (int i = 0; i < 4; i++) {
        const int l = i * 32 + w * 8 + (lane >> 3);
        const int cc = lane & 7;
        const size_t gq = (size_t)(c * CHUNK + l) * 2048 + h * 64 + ((cc ^ (l & 7)) << 3);
        gl_lds16(qkb + gq,        &q_l[(i * 32 + w * 8) * 64 + lane * 8]);
        gl_lds16(qkb + gq + 1024, &k_l[(i * 32 + w * 8) * 64 + lane * 8]);
        const int d0 = w * 16 + i * 4 + (lane >> 4);
        const int cv = lane & 15;
        gl_lds16(vT_b + (size_t)(h * 64 + d0) * 2048 + c * 128 + ((cv ^ (d0 & 7)) << 3),
                 &vT_l[(w * 16 + i * 4) * 128 + lane * 8]);
    }
    {
        const int e = t >> 2, db = (t & 3) * 16;
        float kv[16];
#pragma unroll
        for (int i = 0; i < 16; i++) kv[i] = 0.f;
        for (int cp = 0; cp < c; cp++) {
            const float* Sp = S_ws + ((size_t)(h * NCHUNK + cp) << 12) + e * 64 + db;
#pragma unroll
            for (int g = 0; g < 4; g++) {
                float4 s4 = *(const float4*)(Sp + g * 4);
                kv[g * 4 + 0] += s4.x; kv[g * 4 + 1] += s4.y;
                kv[g * 4 + 2] += s4.z; kv[g * 4 + 3] += s4.w;
            }
        }
#pragma unroll
        for (int g = 0; g < 4; g++) {
            ushortx4 u = { f2bf(kv[g * 4 + 0]), f2bf(kv[g * 4 + 1]),
                           f2bf(kv[g * 4 + 2]), f2bf(kv[g * 4 + 3]) };
            *(ushortx4*)&kvT_l[e * 72 + db + g * 4] = u;
        }
        if (t < 64) {
            float s = 0.f;
            for (int cp = 0; cp < c; cp++) s += ksum_ws[(h * NCHUNK + cp) * 64 + t];
            kpref[t] = s;
        }
    }
    __syncthreads();

    const int pm = (w >> 1) * 64, pn = (w & 1) * 64;
    floatx4 pacc[4][4];
#pragma unroll
    for (int i = 0; i < 4; i++)
#pragma unroll
        for (int j = 0; j < 4; j++) pacc[i][j] = (floatx4)0.0f;
#pragma unroll
    for (int s = 0; s < 2; s++) {
        const int rc = (((s * 4 + q4) ^ (ln & 7)) << 3);
        short8 af[4], bfr[4];
#pragma unroll
        for (int i = 0; i < 4; i++)
            af[i] = *(const short8*)&q_l[(pm + i * 16 + ln) * 64 + rc];
#pragma unroll
        for (int j = 0; j < 4; j++)
            bfr[j] = *(const short8*)&k_l[(pn + j * 16 + ln) * 64 + rc];
#pragma unroll
        for (int i = 0; i < 4; i++)
#pragma unroll
            for (int j = 0; j < 4; j++)
                pacc[i][j] = __builtin_amdgcn_mfma_f32_16x16x32_bf16(af[i], bfr[j], pacc[i][j], 0, 0, 0);
    }
#pragma unroll
    for (int i = 0; i < 4; i++)
#pragma unroll
        for (int r = 0; r < 4; r++) {
            int rowi = pm + i * 16 + q4 * 4 + r;
            float rs = 0.f;
#pragma unroll
            for (int j = 0; j < 4; j++) {
                int col = pn + j * 16 + ln;
                float p = pacc[i][j][r];
                if (col > rowi) p = 0.f;
                pacc[i][j][r] = p;
                rs += p;
            }
#pragma unroll
            for (int off = 1; off < 16; off <<= 1) rs += __shfl_xor(rs, off, 64);
            if (ln == 0) denom2[(w & 1) * 128 + rowi] = rs;
        }
    const int ob = w * 32;
    floatx4 oacc[2][4];
#pragma unroll
    for (int i = 0; i < 2; i++)
#pragma unroll
        for (int j = 0; j < 4; j++) oacc[i][j] = (floatx4)0.0f;
#pragma unroll
    for (int s = 0; s < 2; s++) {
        const int rc = (((s * 4 + q4) ^ (ln & 7)) << 3);
        short8 af[2], bfr[4];
#pragma unroll
        for (int i2 = 0; i2 < 2; i2++)
            af[i2] = *(const short8*)&q_l[(ob + i2 * 16 + ln) * 64 + rc];
#pragma unroll
        for (int j = 0; j < 4; j++)
            bfr[j] = *(const short8*)&kvT_l[(j * 16 + ln) * 72 + s * 32 + q4 * 8];
#pragma unroll
        for (int i2 = 0; i2 < 2; i2++)
#pragma unroll
            for (int j = 0; j < 4; j++)
                oacc[i2][j] = __builtin_amdgcn_mfma_f32_16x16x32_bf16(af[i2], bfr[j], oacc[i2][j], 0, 0, 0);
    }
    __syncthreads();
    if (t < 128) {
        float s = 0.f;
#pragma unroll
        for (int c8 = 0; c8 < 8; c8++) {
            ushortx8 v8 = *(const ushortx8*)&q_l[t * 64 + ((c8 ^ (t & 7)) << 3)];
#pragma unroll
            for (int jj = 0; jj < 8; jj++) s += bf2f(v8[jj]) * kpref[c8 * 8 + jj];
        }
        denom2[t] += s;
    }
    __syncthreads();
#pragma unroll
    for (int i = 0; i < 4; i++)
#pragma unroll
        for (int j = 0; j < 4; j++)
#pragma unroll
            for (int r = 0; r < 4; r++) {
                int rowi = pm + i * 16 + q4 * 4 + r;
                int col = pn + j * 16 + ln;
                P_l[rowi * 136 + col] = f2bf(pacc[i][j][r]);
            }
    __syncthreads();
    for (int ks = 0; ks <= w; ks++) {
        short8 af[2], bfr[4];
#pragma unroll
        for (int i2 = 0; i2 < 2; i2++)
            af[i2] = *(const short8*)&P_l[(ob + i2 * 16 + ln) * 136 + ks * 32 + q4 * 8];
        const int rc = (((ks * 4 + q4) ^ (ln & 7)) << 3);
#pragma unroll
        for (int j = 0; j < 4; j++)
            bfr[j] = *(const short8*)&vT_l[(j * 16 + ln) * 128 + rc];
#pragma unroll
        for (int i2 = 0; i2 < 2; i2++)
#pragma unroll
            for (int j = 0; j < 4; j++)
                oacc[i2][j] = __builtin_amdgcn_mfma_f32_16x16x32_bf16(af[i2], bfr[j], oacc[i2][j], 0, 0, 0);
    }
#pragma unroll
    for (int i2 = 0; i2 < 2; i2++)
#pragma unroll
        for (int j = 0; j < 4; j++)
#pragma unroll
            for (int r = 0; r < 4; r++) {
                int rowi = ob + i2 * 16 + q4 * 4 + r;
                int e = j * 16 + ln;
                float den = denom2[rowi] + denom2[128 + rowi];
                den = fmaxf(den, 1e-6f);
                float val = oacc[i2][j][r] / den;
                attnb[(size_t)(c * CHUNK + rowi) * 1024 + h * 64 + e] = f2bf(val);
            }
    __syncthreads();
}

// ---------------- phase 4: one 64x64 out tile (R3-verified body) ------------
__device__ __forceinline__ void out_tile(int tile, u16* smem,
    const u16* __restrict__ A, const u16* __restrict__ Bm, float* __restrict__ out)
{
    u16* As = smem;           // [64][64]
    u16* Bs = smem + 4096;    // [64][64]
    const int n0 = (tile & 15) * 64, m0 = (tile >> 4) * 64;
    const int t = threadIdx.x;
    const int lane = t & 63, wave = t >> 6;
    const int ln = lane & 15, q4 = lane >> 4;
    const int wm = (wave >> 1) * 32, wn = (wave & 1) * 32;
    const int r_in = t >> 3;
    const int csw = (((t & 7) ^ (r_in & 7)) << 3);

    const u16* Ag = A + (size_t)(m0 + r_in) * 1024 + csw;
    const u16* Bg = Bm + (size_t)(n0 + r_in) * 1024 + csw;

    floatx4 acc[2][2];
#pragma unroll
    for (int i = 0; i < 2; i++)
#pragma unroll
        for (int j = 0; j < 2; j++) acc[i][j] = (floatx4)0.0f;

    for (int k0 = 0; k0 < 1024; k0 += 64) {
        __syncthreads();
        gl_lds16(Ag, &As[t * 8]);
        gl_lds16(Ag + 32 * 1024, &As[2048 + t * 8]);
        gl_lds16(Bg, &Bs[t * 8]);
        gl_lds16(Bg + 32 * 1024, &Bs[2048 + t * 8]);
        Ag += 64; Bg += 64;
        __syncthreads();
#pragma unroll
        for (int s = 0; s < 2; s++) {
            const int rc = (((s * 4 + q4) ^ (ln & 7)) << 3);
            short8 af[2], bfr[2];
#pragma unroll
            for (int i = 0; i < 2; i++)
                af[i] = *(const short8*)&As[(wm + i * 16 + ln) * 64 + rc];
#pragma unroll
            for (int j = 0; j < 2; j++)
                bfr[j] = *(const short8*)&Bs[(wn + j * 16 + ln) * 64 + rc];
#pragma unroll
            for (int i = 0; i < 2; i++)
#pragma unroll
                for (int j = 0; j < 2; j++)
                    acc[i][j] = __builtin_amdgcn_mfma_f32_16x16x32_bf16(af[i], bfr[j], acc[i][j], 0, 0, 0);
        }
    }
#pragma unroll
    for (int i = 0; i < 2; i++)
#pragma unroll
        for (int j = 0; j < 2; j++)
#pragma unroll
            for (int r = 0; r < 4; r++) {
                int m = m0 + wm + i * 16 + q4 * 4 + r;
                int n = n0 + wn + j * 16 + ln;
                out[(size_t)m * 1024 + n] = acc[i][j][r];
            }
    __syncthreads();
}

// ---------------- the single persistent mega-kernel -------------------------
__global__ __launch_bounds__(256, 2)
void fla_mega(const float* __restrict__ x,  const float* __restrict__ Wq,
              const float* __restrict__ Wk, const float* __restrict__ Wv,
              const float* __restrict__ Wo, float* __restrict__ out,
              u16* __restrict__ xb, u16* __restrict__ Wb, u16* __restrict__ Wob,
              u16* __restrict__ qkb, u16* __restrict__ kT_b, u16* __restrict__ vT_b,
              float* __restrict__ S_ws, float* __restrict__ ksum_ws,
              u16* __restrict__ attnb, int* __restrict__ bar)
{
    __shared__ __align__(16) u16 smem[29824];  // 59648 B -> 2 blocks/CU

    // ---- phase 0: fp32 -> bf16 convert (grid-stride) ----
    {
        const int total4 = 1572864;
        for (int idx = blockIdx.x * 256 + threadIdx.x; idx < total4; idx += NBLK * 256) {
            const float4* src; u16* dst; int off;
            if (idx < 524288)       { src = (const float4*)x;  dst = xb;           off = idx; }
            else if (idx < 786432)  { src = (const float4*)Wq; dst = Wb;           off = idx - 524288; }
            else if (idx < 1048576) { src = (const float4*)Wk; dst = Wb + 1048576; off = idx - 786432; }
            else if (idx < 1310720) { src = (const float4*)Wv; dst = Wb + 2097152; off = idx - 1048576; }
            else                    { src = (const float4*)Wo; dst = Wob;          off = idx - 1310720; }
            float4 v = src[off];
            ushortx4 u = { f2bf(v.x), f2bf(v.y), f2bf(v.z), f2bf(v.w) };
            *(ushortx4*)(dst + (size_t)off * 4) = u;
        }
    }
    gridbar(bar, 0);

    // ---- phase 1: qkv GEMM, 384 tiles of 128x128 (exactly 1 per block) ----
    qkv_tile(blockIdx.x, smem, xb, Wb, qkb, kT_b, vT_b);
    gridbar(bar, 1);

    // ---- phase 2: chunk stats, 256 (c,h) bodies ----
    if (blockIdx.x < 256)
        chunk_stats_body(blockIdx.x & 15, blockIdx.x >> 4, smem, kT_b, vT_b, S_ws, ksum_ws);
    gridbar(bar, 2);

    // ---- phase 3: attention, 256 (c,h) bodies ----
    if (blockIdx.x < 256)
        attn_body(blockIdx.x & 15, blockIdx.x >> 4, smem, qkb, vT_b, S_ws, ksum_ws, attnb);
    gridbar(bar, 3);

    // ---- phase 4: out GEMM, 512 tiles of 64x64 ----
    for (int tile = blockIdx.x; tile < 512; tile += NBLK)
        out_tile(tile, smem, attnb, Wob, out);
}

// ---------------------------------------------------------------------------
// Workspace (~36.3 MB of >=256 MB):
//   xb    @  0 MB   4 MB | Wb @ 4 MB  6 MB | Wob @ 10 MB  2 MB
//   qkb   @ 12 MB   8 MB | kT_b @ 20 MB 4 MB | vT_b @ 24 MB 4 MB
//   S_ws  @ 28 MB   4 MB | ksum @ 32 MB 256 KB | attnb @ 33 MB 4 MB
//   bar   @ 37 MB   64 B  (zeroed via hipMemsetAsync each call)
// ---------------------------------------------------------------------------
extern "C" void kernel_launch(void* const* d_in, const int* in_sizes, int n_in,
                              void* d_out, int out_size, void* d_ws, size_t ws_size,
                              hipStream_t stream)
{
    const float* x  = (const float*)d_in[0];
    const float* Wq = (const float*)d_in[1];
    const float* Wk = (const float*)d_in[2];
    const float* Wv = (const float*)d_in[3];
    const float* Wo = (const float*)d_in[4];
    float* out = (float*)d_out;

    char* ws = (char*)d_ws;
    const size_t MB = 1024 * 1024;
    u16* xb    = (u16*)(ws);
    u16* Wb    = (u16*)(ws + 4 * MB);
    u16* Wob   = (u16*)(ws + 10 * MB);
    u16* qkb   = (u16*)(ws + 12 * MB);
    u16* kT_b  = (u16*)(ws + 20 * MB);
    u16* vT_b  = (u16*)(ws + 24 * MB);
    float* S_ws    = (float*)(ws + 28 * MB);
    float* ksum_ws = (float*)(ws + 32 * MB);
    u16* attnb = (u16*)(ws + 33 * MB);
    int* bar   = (int*)(ws + 37 * MB);

    hipMemsetAsync(bar, 0, 64, stream);  // graph-capturable; resets barrier
    fla_mega<<<dim3(NBLK), dim3(256), 0, stream>>>(
        x, Wq, Wk, Wv, Wo, out,
        xb, Wb, Wob, qkb, kT_b, vT_b, S_ws, ksum_ws, attnb, bar);
}

// Round 6
// 132.346 us; speedup vs baseline: 4.6708x; 4.6708x over previous
//
#include <hip/hip_runtime.h>
#include <hip/hip_bf16.h>

typedef __attribute__((ext_vector_type(8))) short short8;
typedef __attribute__((ext_vector_type(4))) float floatx4;
typedef __attribute__((ext_vector_type(8))) unsigned short ushortx8;
typedef __attribute__((ext_vector_type(4))) unsigned short ushortx4;
typedef unsigned short u16;

#define NH 16
#define SEQ 2048
#define CHUNK 128
#define NCHUNK 16

__device__ __forceinline__ u16 f2bf(float f) {
    union { float f; unsigned u; } v; v.f = f;
    unsigned r = v.u + 0x7fffu + ((v.u >> 16) & 1u);
    return (u16)(r >> 16);
}
__device__ __forceinline__ float bf2f(u16 u) {
    union { unsigned u; float f; } v; v.u = ((unsigned)u) << 16;
    return v.f;
}
__device__ __forceinline__ void gl_lds16(const u16* g, u16* l) {
    __builtin_amdgcn_global_load_lds(
        (const __attribute__((address_space(1))) void*)g,
        (__attribute__((address_space(3))) void*)l,
        16, 0, 0);
}

// ---------------------------------------------------------------------------
// Kernel 0: fp32 -> bf16 of x, Wq|Wk|Wv (fused rows), Wo. ~36 MB traffic.
// ---------------------------------------------------------------------------
__global__ __launch_bounds__(256)
void convert_all(const float* __restrict__ x,  const float* __restrict__ Wq,
                 const float* __restrict__ Wk, const float* __restrict__ Wv,
                 const float* __restrict__ Wo,
                 u16* __restrict__ xb, u16* __restrict__ Wb, u16* __restrict__ Wob)
{
    const int total4 = 1572864;  // 6M floats / 4
    for (int idx = blockIdx.x * 256 + threadIdx.x; idx < total4; idx += gridDim.x * 256) {
        const float4* src; u16* dst; int off;
        if (idx < 524288)       { src = (const float4*)x;  dst = xb;            off = idx; }
        else if (idx < 786432)  { src = (const float4*)Wq; dst = Wb;            off = idx - 524288; }
        else if (idx < 1048576) { src = (const float4*)Wk; dst = Wb + 1048576;  off = idx - 786432; }
        else if (idx < 1310720) { src = (const float4*)Wv; dst = Wb + 2097152;  off = idx - 1048576; }
        else                    { src = (const float4*)Wo; dst = Wob;           off = idx - 1310720; }
        float4 v = src[off];
        ushortx4 u = { f2bf(v.x), f2bf(v.y), f2bf(v.z), f2bf(v.w) };
        *(ushortx4*)(dst + (size_t)off * 4) = u;
    }
}

// ---------------------------------------------------------------------------
// Kernel 1: fused QKV GEMM, 64x128 tile (768 blocks = 3/CU), BK=64 (R3 body).
// Epilogue: q row-major+elu; k row-major+elu AND kT; v -> vT only.
// ---------------------------------------------------------------------------
__global__ __launch_bounds__(256, 3)
void qkv_gemm64(const u16* __restrict__ A, const u16* __restrict__ Bm,
                u16* __restrict__ qkb, u16* __restrict__ kT_b, u16* __restrict__ vT_b)
{
    __shared__ u16 As[64 * 64];
    __shared__ u16 Bs[128 * 64];
    const int n0 = blockIdx.x * 128, m0 = blockIdx.y * 64;
    const int t = threadIdx.x;
    const int lane = t & 63, wave = t >> 6;
    const int ln = lane & 15, q4 = lane >> 4;
    const int wm = (wave >> 1) * 32, wn = (wave & 1) * 64;
    const int r_in = t >> 3;
    const int csw = (((t & 7) ^ (r_in & 7)) << 3);

    const u16* Ag = A + (size_t)(m0 + r_in) * 1024 + csw;
    const u16* Bg = Bm + (size_t)(n0 + r_in) * 1024 + csw;

    floatx4 acc[2][4];
#pragma unroll
    for (int i = 0; i < 2; i++)
#pragma unroll
        for (int j = 0; j < 4; j++) acc[i][j] = (floatx4)0.0f;

    for (int k0 = 0; k0 < 1024; k0 += 64) {
        if (k0) __syncthreads();
        gl_lds16(Ag, &As[t * 8]);
        gl_lds16(Ag + 32 * 1024, &As[2048 + t * 8]);
#pragma unroll
        for (int i = 0; i < 4; i++)
            gl_lds16(Bg + (size_t)i * 32 * 1024, &Bs[i * 2048 + t * 8]);
        Ag += 64; Bg += 64;
        __syncthreads();
#pragma unroll
        for (int s = 0; s < 2; s++) {
            const int rc = (((s * 4 + q4) ^ (ln & 7)) << 3);
            short8 af[2], bfr[4];
#pragma unroll
            for (int i = 0; i < 2; i++)
                af[i] = *(const short8*)&As[(wm + i * 16 + ln) * 64 + rc];
#pragma unroll
            for (int j = 0; j < 4; j++)
                bfr[j] = *(const short8*)&Bs[(wn + j * 16 + ln) * 64 + rc];
#pragma unroll
            for (int i = 0; i < 2; i++)
#pragma unroll
                for (int j = 0; j < 4; j++)
                    acc[i][j] = __builtin_amdgcn_mfma_f32_16x16x32_bf16(af[i], bfr[j], acc[i][j], 0, 0, 0);
        }
    }
    const int grp = n0 >> 10;  // 0=q 1=k 2=v (block-uniform)
#pragma unroll
    for (int i = 0; i < 2; i++)
#pragma unroll
        for (int j = 0; j < 4; j++) {
            const int mb = m0 + wm + i * 16 + q4 * 4;
            const int n = n0 + wn + j * 16 + ln;
            const int nh = n & 1023, h = nh >> 6, e = nh & 63;
            float vals[4];
#pragma unroll
            for (int r = 0; r < 4; r++) {
                float v = acc[i][j][r];
                if (grp < 2) v = (v > 0.f) ? (v + 1.f) : __expf(v);
                vals[r] = v;
            }
            if (grp == 0) {
#pragma unroll
                for (int r = 0; r < 4; r++) qkb[(size_t)(mb + r) * 2048 + nh] = f2bf(vals[r]);
            } else if (grp == 1) {
#pragma unroll
                for (int r = 0; r < 4; r++) qkb[(size_t)(mb + r) * 2048 + 1024 + nh] = f2bf(vals[r]);
                ushortx4 u = { f2bf(vals[0]), f2bf(vals[1]), f2bf(vals[2]), f2bf(vals[3]) };
                *(ushortx4*)&kT_b[(size_t)(h * 64 + e) * 2048 + mb] = u;
            } else {
                ushortx4 u = { f2bf(vals[0]), f2bf(vals[1]), f2bf(vals[2]), f2bf(vals[3]) };
                *(ushortx4*)&vT_b[(size_t)(h * 64 + e) * 2048 + mb] = u;
            }
        }
}

// ---------------------------------------------------------------------------
// Kernel 2: FUSED chunk-state + attention per (c,h). grid (16,16).
//   Phase A: KV_pref[d][e] = K_{0:c}^T V_{0:c} via MFMA over c staged chunks;
//            kpref[d] = sum_l K[l][d] via ones-MFMA (A=1), 0 extra LDS reads.
//   Phase B: P = QK^T (masked) -> denom rowsum; O = P V + Q KV_pref; divide.
// LDS 59648 B, time-aliased; P stored XOR-swizzled in [128][128].
// ---------------------------------------------------------------------------
__global__ __launch_bounds__(256, 1)
void attn_fused(const u16* __restrict__ qkb, const u16* __restrict__ kT_b,
                const u16* __restrict__ vT_b, u16* __restrict__ attnb)
{
    __shared__ __align__(16) u16 smem[29824];   // 59648 B
    u16* kT_s  = smem;           // [64][128]  phase-A staging
    u16* vT_s  = smem + 8192;    // [64][128]  phase-A staging
    u16* vT_l  = smem;           // [64][128]  own chunk (over kT_s)
    u16* q_l   = smem + 8192;    // [128][64]  (over vT_s)
    u16* k_l   = smem + 16384;   // [128][64]
    u16* P_l   = smem + 8192;    // [128][128] swizzled (over q_l+k_l when dead)
    u16* kvT_l = smem + 24576;   // [64][72]
    float* kpref  = (float*)(smem + 29184);  // [64]
    float* denom2 = (float*)(smem + 29312);  // [2][128]

    const int c = blockIdx.x, h = blockIdx.y;
    const int t = threadIdx.x;
    const int lane = t & 63, w = t >> 6;
    const int ln = lane & 15, q4 = lane >> 4;

    // ---- phase A: prefix KV state + kpref over chunks 0..c-1 ----
    floatx4 sacc[4];
    floatx4 sksum = (floatx4)0.0f;
#pragma unroll
    for (int j = 0; j < 4; j++) sacc[j] = (floatx4)0.0f;
    const short one_bf = (short)0x3F80;
    const short8 a_ones = { one_bf, one_bf, one_bf, one_bf,
                            one_bf, one_bf, one_bf, one_bf };
    for (int cp = 0; cp < c; cp++) {
        __syncthreads();               // prev chunk's LDS reads done
#pragma unroll
        for (int i = 0; i < 4; i++) {
            const int d0 = w * 16 + i * 4 + (lane >> 4);
            const int cc = lane & 15;
            const size_t gsrc = (size_t)(h * 64 + d0) * 2048 + cp * 128 + ((cc ^ (d0 & 7)) << 3);
            gl_lds16(kT_b + gsrc, &kT_s[(w * 16 + i * 4) * 128 + lane * 8]);
            gl_lds16(vT_b + gsrc, &vT_s[(w * 16 + i * 4) * 128 + lane * 8]);
        }
        __syncthreads();               // drain DMA
#pragma unroll
        for (int ks = 0; ks < 4; ks++) {
            const int rc = (((ks * 4 + q4) ^ (ln & 7)) << 3);
            short8 af = *(const short8*)&kT_s[(w * 16 + ln) * 128 + rc];
            sksum = __builtin_amdgcn_mfma_f32_16x16x32_bf16(a_ones, af, sksum, 0, 0, 0);
#pragma unroll
            for (int j = 0; j < 4; j++) {
                short8 bfr = *(const short8*)&vT_s[(j * 16 + ln) * 128 + rc];
                sacc[j] = __builtin_amdgcn_mfma_f32_16x16x32_bf16(af, bfr, sacc[j], 0, 0, 0);
            }
        }
    }
    __syncthreads();                   // phase-A LDS reads done; regions reusable

    // ---- own-chunk staging (async) + publish kvT/kpref ----
#pragma unroll
    for (int i = 0; i < 4; i++) {
        const int l = i * 32 + w * 8 + (lane >> 3);
        const int cc = lane & 7;
        const size_t gq = (size_t)(c * CHUNK + l) * 2048 + h * 64 + ((cc ^ (l & 7)) << 3);
        gl_lds16(qkb + gq,        &q_l[(i * 32 + w * 8) * 64 + lane * 8]);
        gl_lds16(qkb + gq + 1024, &k_l[(i * 32 + w * 8) * 64 + lane * 8]);
        const int d0 = w * 16 + i * 4 + (lane >> 4);
        const int cv = lane & 15;
        gl_lds16(vT_b + (size_t)(h * 64 + d0) * 2048 + c * 128 + ((cv ^ (d0 & 7)) << 3),
                 &vT_l[(w * 16 + i * 4) * 128 + lane * 8]);
    }
    // kvT_l[e][d] = KV_pref[d][e]; thread owns d = w*16+q4*4+r (r contig), e = j*16+ln
#pragma unroll
    for (int j = 0; j < 4; j++) {
        const int e = j * 16 + ln;
        ushortx4 u = { f2bf(sacc[j][0]), f2bf(sacc[j][1]), f2bf(sacc[j][2]), f2bf(sacc[j][3]) };
        *(ushortx4*)&kvT_l[e * 72 + w * 16 + q4 * 4] = u;
    }
    if (q4 == 0) kpref[w * 16 + ln] = sksum[0];  // ones-MFMA: col d = w*16+ln
    __syncthreads();                   // drains own DMAs; kvT/kpref visible

    // ---- P = QK^T : wave quadrant, 64x64, K=64 ----
    const int pm = (w >> 1) * 64, pn = (w & 1) * 64;
    floatx4 pacc[4][4];
#pragma unroll
    for (int i = 0; i < 4; i++)
#pragma unroll
        for (int j = 0; j < 4; j++) pacc[i][j] = (floatx4)0.0f;
#pragma unroll
    for (int s = 0; s < 2; s++) {
        const int rc = (((s * 4 + q4) ^ (ln & 7)) << 3);
        short8 af[4], bfr[4];
#pragma unroll
        for (int i = 0; i < 4; i++)
            af[i] = *(const short8*)&q_l[(pm + i * 16 + ln) * 64 + rc];
#pragma unroll
        for (int j = 0; j < 4; j++)
            bfr[j] = *(const short8*)&k_l[(pn + j * 16 + ln) * 64 + rc];
#pragma unroll
        for (int i = 0; i < 4; i++)
#pragma unroll
            for (int j = 0; j < 4; j++)
                pacc[i][j] = __builtin_amdgcn_mfma_f32_16x16x32_bf16(af[i], bfr[j], pacc[i][j], 0, 0, 0);
    }
    // ---- causal mask + rowsum (intra denominator) ----
#pragma unroll
    for (int i = 0; i < 4; i++)
#pragma unroll
        for (int r = 0; r < 4; r++) {
            int rowi = pm + i * 16 + q4 * 4 + r;
            float rs = 0.f;
#pragma unroll
            for (int j = 0; j < 4; j++) {
                int col = pn + j * 16 + ln;
                float p = pacc[i][j][r];
                if (col > rowi) p = 0.f;
                pacc[i][j][r] = p;
                rs += p;
            }
#pragma unroll
            for (int off = 1; off < 16; off <<= 1) rs += __shfl_xor(rs, off, 64);
            if (ln == 0) denom2[(w & 1) * 128 + rowi] = rs;
        }
    // ---- O_inter = Q @ KV_pref : wave rows ob..ob+31 ----
    const int ob = w * 32;
    floatx4 oacc[2][4];
#pragma unroll
    for (int i = 0; i < 2; i++)
#pragma unroll
        for (int j = 0; j < 4; j++) oacc[i][j] = (floatx4)0.0f;
#pragma unroll
    for (int s = 0; s < 2; s++) {
        const int rc = (((s * 4 + q4) ^ (ln & 7)) << 3);
        short8 af[2], bfr[4];
#pragma unroll
        for (int i2 = 0; i2 < 2; i2++)
            af[i2] = *(const short8*)&q_l[(ob + i2 * 16 + ln) * 64 + rc];
#pragma unroll
        for (int j = 0; j < 4; j++)
            bfr[j] = *(const short8*)&kvT_l[(j * 16 + ln) * 72 + s * 32 + q4 * 8];
#pragma unroll
        for (int i2 = 0; i2 < 2; i2++)
#pragma unroll
            for (int j = 0; j < 4; j++)
                oacc[i2][j] = __builtin_amdgcn_mfma_f32_16x16x32_bf16(af[i2], bfr[j], oacc[i2][j], 0, 0, 0);
    }
    __syncthreads();   // denom rowsums visible; q/k/kvT MFMA reads done
    // ---- denominator inter part: q_i . kpref (q_l swizzled walk) ----
    if (t < 128) {
        float s = 0.f;
#pragma unroll
        for (int c8 = 0; c8 < 8; c8++) {
            ushortx8 v8 = *(const ushortx8*)&q_l[t * 64 + ((c8 ^ (t & 7)) << 3)];
#pragma unroll
            for (int jj = 0; jj < 8; jj++) s += bf2f(v8[jj]) * kpref[c8 * 8 + jj];
        }
        denom2[t] += s;
    }
    __syncthreads();   // q_l reads done; safe to overwrite with P
    // ---- write masked P, bf16, XOR-swizzled [128][128] ----
#pragma unroll
    for (int i = 0; i < 4; i++)
#pragma unroll
        for (int j = 0; j < 4; j++)
#pragma unroll
            for (int r = 0; r < 4; r++) {
                int rowi = pm + i * 16 + q4 * 4 + r;
                int col = pn + j * 16 + ln;
                P_l[rowi * 128 + (col ^ ((rowi & 7) << 3))] = f2bf(pacc[i][j][r]);
            }
    __syncthreads();
    // ---- O_intra = P @ V : causal skip (ks <= wave) ----
    for (int ks = 0; ks <= w; ks++) {
        short8 af[2], bfr[4];
#pragma unroll
        for (int i2 = 0; i2 < 2; i2++) {
            const int row = ob + i2 * 16 + ln;
            af[i2] = *(const short8*)&P_l[row * 128 + ((((ks * 4 + q4) ^ (row & 7))) << 3)];
        }
        const int rc = (((ks * 4 + q4) ^ (ln & 7)) << 3);
#pragma unroll
        for (int j = 0; j < 4; j++)
            bfr[j] = *(const short8*)&vT_l[(j * 16 + ln) * 128 + rc];
#pragma unroll
        for (int i2 = 0; i2 < 2; i2++)
#pragma unroll
            for (int j = 0; j < 4; j++)
                oacc[i2][j] = __builtin_amdgcn_mfma_f32_16x16x32_bf16(af[i2], bfr[j], oacc[i2][j], 0, 0, 0);
    }
    // ---- normalize + store ----
#pragma unroll
    for (int i2 = 0; i2 < 2; i2++)
#pragma unroll
        for (int j = 0; j < 4; j++)
#pragma unroll
            for (int r = 0; r < 4; r++) {
                int rowi = ob + i2 * 16 + q4 * 4 + r;
                int e = j * 16 + ln;
                float den = denom2[rowi] + denom2[128 + rowi];
                den = fmaxf(den, 1e-6f);
                float val = oacc[i2][j][r] / den;
                attnb[(size_t)(c * CHUNK + rowi) * 1024 + h * 64 + e] = f2bf(val);
            }
}

// ---------------------------------------------------------------------------
// Kernel 3: out = attn @ Wo^T, 64x64 tile (512 blocks = 2/CU), fp32 out.
// ---------------------------------------------------------------------------
__global__ __launch_bounds__(256, 3)
void out_gemm64(const u16* __restrict__ A, const u16* __restrict__ Bm,
                float* __restrict__ out)
{
    __shared__ u16 As[64 * 64];
    __shared__ u16 Bs[64 * 64];
    const int n0 = blockIdx.x * 64, m0 = blockIdx.y * 64;
    const int t = threadIdx.x;
    const int lane = t & 63, wave = t >> 6;
    const int ln = lane & 15, q4 = lane >> 4;
    const int wm = (wave >> 1) * 32, wn = (wave & 1) * 32;
    const int r_in = t >> 3;
    const int csw = (((t & 7) ^ (r_in & 7)) << 3);

    const u16* Ag = A + (size_t)(m0 + r_in) * 1024 + csw;
    const u16* Bg = Bm + (size_t)(n0 + r_in) * 1024 + csw;

    floatx4 acc[2][2];
#pragma unroll
    for (int i = 0; i < 2; i++)
#pragma unroll
        for (int j = 0; j < 2; j++) acc[i][j] = (floatx4)0.0f;

    for (int k0 = 0; k0 < 1024; k0 += 64) {
        if (k0) __syncthreads();
        gl_lds16(Ag, &As[t * 8]);
        gl_lds16(Ag + 32 * 1024, &As[2048 + t * 8]);
        gl_lds16(Bg, &Bs[t * 8]);
        gl_lds16(Bg + 32 * 1024, &Bs[2048 + t * 8]);
        Ag += 64; Bg += 64;
        __syncthreads();
#pragma unroll
        for (int s = 0; s < 2; s++) {
            const int rc = (((s * 4 + q4) ^ (ln & 7)) << 3);
            short8 af[2], bfr[2];
#pragma unroll
            for (int i = 0; i < 2; i++)
                af[i] = *(const short8*)&As[(wm + i * 16 + ln) * 64 + rc];
#pragma unroll
            for (int j = 0; j < 2; j++)
                bfr[j] = *(const short8*)&Bs[(wn + j * 16 + ln) * 64 + rc];
#pragma unroll
            for (int i = 0; i < 2; i++)
#pragma unroll
                for (int j = 0; j < 2; j++)
                    acc[i][j] = __builtin_amdgcn_mfma_f32_16x16x32_bf16(af[i], bfr[j], acc[i][j], 0, 0, 0);
        }
    }
#pragma unroll
    for (int i = 0; i < 2; i++)
#pragma unroll
        for (int j = 0; j < 2; j++)
#pragma unroll
            for (int r = 0; r < 4; r++) {
                int m = m0 + wm + i * 16 + q4 * 4 + r;
                int n = n0 + wn + j * 16 + ln;
                out[(size_t)m * 1024 + n] = acc[i][j][r];
            }
}

// ---------------------------------------------------------------------------
// Workspace (32 MB of >=256 MB):
//   xb @ 0 (4MB) | Wb @ 4 (6MB) | Wob @ 10 (2MB) | qkb @ 12 (8MB)
//   kT_b @ 20 (4MB) | vT_b @ 24 (4MB) | attnb @ 28 (4MB)
// ---------------------------------------------------------------------------
extern "C" void kernel_launch(void* const* d_in, const int* in_sizes, int n_in,
                              void* d_out, int out_size, void* d_ws, size_t ws_size,
                              hipStream_t stream)
{
    const float* x  = (const float*)d_in[0];
    const float* Wq = (const float*)d_in[1];
    const float* Wk = (const float*)d_in[2];
    const float* Wv = (const float*)d_in[3];
    const float* Wo = (const float*)d_in[4];
    float* out = (float*)d_out;

    char* ws = (char*)d_ws;
    const size_t MB = 1024 * 1024;
    u16* xb    = (u16*)(ws);
    u16* Wb    = (u16*)(ws + 4 * MB);
    u16* Wob   = (u16*)(ws + 10 * MB);
    u16* qkb   = (u16*)(ws + 12 * MB);
    u16* kT_b  = (u16*)(ws + 20 * MB);
    u16* vT_b  = (u16*)(ws + 24 * MB);
    u16* attnb = (u16*)(ws + 28 * MB);

    convert_all<<<2048, 256, 0, stream>>>(x, Wq, Wk, Wv, Wo, xb, Wb, Wob);
    qkv_gemm64<<<dim3(24, 32), 256, 0, stream>>>(xb, Wb, qkb, kT_b, vT_b);
    attn_fused<<<dim3(NCHUNK, NH), 256, 0, stream>>>(qkb, kT_b, vT_b, attnb);
    out_gemm64<<<dim3(16, 32), 256, 0, stream>>>(attnb, Wob, out);
}